// Round 7
// baseline (196.029 us; speedup 1.0000x reference)
//
#include <hip/hip_runtime.h>
#include <hip/hip_bf16.h>

#define N_Q 256
#define M_S 1024
#define DD 512
#define HH 512

typedef __attribute__((ext_vector_type(8))) short short8;
typedef __attribute__((ext_vector_type(8))) __bf16 bf16x8;
typedef __attribute__((ext_vector_type(16))) float f32x16;
typedef __attribute__((ext_vector_type(2))) __bf16 bf16x2;

union U8 { short8 s; bf16x8 b; };

__device__ __forceinline__ unsigned short f2bf(float f) {
  unsigned int u = __float_as_uint(f);
  u += 0x7FFFu + ((u >> 16) & 1u);
  return (unsigned short)(u >> 16);
}

__device__ __forceinline__ short8 pack8(const float* d) {
#if defined(__has_builtin) && __has_builtin(__builtin_amdgcn_cvt_pk_bf16_f32)
  short8 r;
#pragma unroll
  for (int i = 0; i < 4; ++i) {
    union { bf16x2 v; short s[2]; } u;
    u.v = __builtin_amdgcn_cvt_pk_bf16_f32(d[2 * i], d[2 * i + 1]);
    r[2 * i] = u.s[0];
    r[2 * i + 1] = u.s[1];
  }
  return r;
#else
  short8 r;
#pragma unroll
  for (int i = 0; i < 8; ++i) r[i] = (short)f2bf(d[i]);
  return r;
#endif
}

__device__ __forceinline__ short8 packdiff(float4 e0, float4 e1, float4 s0, float4 s1) {
  float d[8];
  d[0] = fabsf(e0.x - s0.x); d[1] = fabsf(e0.y - s0.y);
  d[2] = fabsf(e0.z - s0.z); d[3] = fabsf(e0.w - s0.w);
  d[4] = fabsf(e1.x - s1.x); d[5] = fabsf(e1.y - s1.y);
  d[6] = fabsf(e1.z - s1.z); d[7] = fabsf(e1.w - s1.w);
  return pack8(d);
}

// W1 [D][H] fp32 -> w1s in MFMA-fragment order.
// Fragment map (verified): w1s[f*512 + l*8 + j] = W1[k][h] with
//   f = (k>>4)*16 + (h>>5), l = ((k>>3)&1)*32 + (h&31), j = k&7.
// Coalesced: 65536 threads, float4 read (4 h per thread), 4 stores.
__global__ __launch_bounds__(1024) void prep_w1s(const float* __restrict__ W1,
                                                 unsigned short* __restrict__ w1s) {
  const int gid = blockIdx.x * 1024 + threadIdx.x;  // 0..65535
  const int k = gid >> 7;                            // 0..511
  const int hq = gid & 127;                          // h-quad
  const float4 w = *(const float4*)(W1 + k * HH + hq * 4);
  const int f = (k >> 4) * 16 + (hq >> 3);
  const int lk = ((k >> 3) & 1) * 32 + (hq & 7) * 4; // l base for i=0
  const int j = k & 7;
  unsigned short* p = w1s + f * 512 + lk * 8 + j;    // stride 8 shorts per h
  p[0]  = f2bf(w.x);
  p[8]  = f2bf(w.y);
  p[16] = f2bf(w.z);
  p[24] = f2bf(w.w);
}

// ---- templated K-phase helpers: OFF in {0,16}, compile-time so all ring ----
// ---- indices / LDS chunk offsets / w1s offsets stay static (rule #20).  ----
template <int OFF>
__device__ __forceinline__ void bpro(U8 (&b)[4][2], const unsigned short* bb) {
#pragma unroll
  for (int s = 0; s < 3; ++s) {
    const int ks = (OFF + s) & 31;
#pragma unroll
    for (int tj = 0; tj < 2; ++tj)
      b[ks & 3][tj].s = *(const short8*)(bb + (ks * 16 + tj) * 512);
  }
}

template <int OFF>
__device__ __forceinline__ void kloop(const short8* As, const unsigned short* bb,
                                      U8 (&b)[4][2], f32x16 (&acc)[4][2],
                                      const int ar0, const int ar1,
                                      const int ar2, const int ar3,
                                      const int khalf, const int ax) {
  U8 a[3][4];
#pragma unroll
  for (int s = 0; s < 2; ++s) {      // A prologue: ks = OFF, OFF+1
    const int ks = (OFF + s) & 31;
    const int c = (ks * 2 + khalf) ^ ax;
    a[ks % 3][0].s = As[ar0 + c];
    a[ks % 3][1].s = As[ar1 + c];
    a[ks % 3][2].s = As[ar2 + c];
    a[ks % 3][3].s = As[ar3 + c];
  }
#pragma unroll
  for (int kk = 0; kk < 32; ++kk) {
    const int ks = (kk + OFF) & 31;
    __builtin_amdgcn_s_setprio(1);
#pragma unroll
    for (int am = 0; am < 4; ++am)
#pragma unroll
      for (int tj = 0; tj < 2; ++tj)
        acc[am][tj] = __builtin_amdgcn_mfma_f32_32x32x16_bf16(
            b[ks & 3][tj].b, a[ks % 3][am].b, acc[am][tj], 0, 0, 0);
    __builtin_amdgcn_s_setprio(0);
    if (kk + 2 < 32) {  // A-frag prefetch, depth 2 (LDS)
      const int ksp = (kk + 2 + OFF) & 31;
      const int cc = (ksp * 2 + khalf) ^ ax;
      a[ksp % 3][0].s = As[ar0 + cc];
      a[ksp % 3][1].s = As[ar1 + cc];
      a[ksp % 3][2].s = As[ar2 + cc];
      a[ksp % 3][3].s = As[ar3 + cc];
    }
    if (kk + 3 < 32) {  // W1-frag prefetch, depth 3 (L2)
      const int ksb = (kk + 3 + OFF) & 31;
#pragma unroll
      for (int tj = 0; tj < 2; ++tj)
        b[ksb & 3][tj].s = *(const short8*)(bb + (ksb * 16 + tj) * 512);
    }
  }
}

// Block: 512 thr = 8 waves. Tile 128 pairs (8 emb x 16 sup) x 512 h x K=512.
// A (diff) staged ONCE into 128 KB LDS, layout [p][c ^ (p&15)] in 16B chunks
// (R7: XOR widened 8->16 slots; read 4-way -> 2-way = free). Wave wid =
// hslice (64 h); every wave covers all 128 pairs (acc[4][2]).
// MFMA operand-swapped: A-op = W1^T frag (regs, L2), B-op = diff frag (LDS);
// C col = pair, row = h => in-lane h-reduce epilogue. setprio kept (R5: +10%).
// R7 main change: PER-WAVE K-START STAGGER. All 8 waves previously ran in
// lockstep from barrier A -> the CU alternated all-MFMA / all-ds_read phases
// (516 + 510 cyc = observed 1100/ks instead of overlapped ~550). Waves with
// phase bit ((wid^(wid>>2))&1) start the K-loop at ks=16 (k-sum is order-
// invariant), so the 2 waves on a SIMD are in opposite phases under either
// wave->SIMD mapping: one feeds the matrix pipe while the other reads LDS.
__global__ __launch_bounds__(512, 2) void support_kernel(
    const float* __restrict__ emb, const float* __restrict__ sup,
    const unsigned short* __restrict__ w1s, const float* __restrict__ b1,
    const float* __restrict__ W2, const float* __restrict__ b2,
    float* __restrict__ out) {
  extern __shared__ short8 As16[];   // [128][64] = 131072 B + psums 4608 B

  const int tid = threadIdx.x;
  const int lane = tid & 63;
  const int wid = tid >> 6;          // 0..7 = hslice (h base = wid*64)
  const int l31 = lane & 31;
  const int khalf = lane >> 5;
  const bool ph = ((wid ^ (wid >> 2)) & 1) != 0;  // K-phase: 0 or 16

  const int m0 = blockIdx.x * 16;
  const int n0 = blockIdx.y * 8;

  // ---- W1-frag prologue (depth 3, phase-dependent), before staging ----
  const unsigned short* bb = w1s + (wid * 2) * 512 + lane * 8;
  U8 b[4][2];
  if (ph) bpro<16>(b, bb); else bpro<0>(b, bb);

  // ---- stage 128p x 512k diffs (once): thread = (emb row rg, k-chunk c) ----
  {
    const int c = tid & 63;
    const int rg = tid >> 6;           // emb row 0..7
    const float* ep = emb + (n0 + rg) * DD + c * 8;
    const float4 e0 = *(const float4*)ep;
    const float4 e1 = *(const float4*)(ep + 4);
    const float* sbase = sup + m0 * DD + c * 8;
#pragma unroll
    for (int j = 0; j < 16; ++j) {     // 16 sup rows; p = rg*16+j, p&15 == j
      const float4 s0 = *(const float4*)(sbase + j * DD);
      const float4 s1 = *(const float4*)(sbase + j * DD + 4);
      As16[(rg * 16 + j) * 64 + (c ^ j)] = packdiff(e0, e1, s0, s1);
    }
  }
  __syncthreads();  // barrier A: full tile visible (needed: ph waves read ks=16)

  // ---- K-loop: 32 steps of 16 k, 8 MFMA each; per-wave staggered start ----
  const int ax = l31 & 15;           // read-side chunk XOR (row&15 == l31&15)
  const int ar0 = (0 * 32 + l31) * 64;
  const int ar1 = (1 * 32 + l31) * 64;
  const int ar2 = (2 * 32 + l31) * 64;
  const int ar3 = (3 * 32 + l31) * 64;

  f32x16 acc[4][2] = {};
  if (ph) kloop<16>(As16, bb, b, acc, ar0, ar1, ar2, ar3, khalf, ax);
  else    kloop<0>(As16, bb, b, acc, ar0, ar1, ar2, ar3, khalf, ax);

  // ---- epilogue: C col = pair (l31 + am*32), row = h: (r&3)+8*(r>>2)+4*khalf
  // In-lane reduce over 64 h per wave; one xor-32 shuffle per am.
  float s0a, s1a, s2a, s3a;
  {
    float sm[4] = {0.f, 0.f, 0.f, 0.f};
#pragma unroll
    for (int tj = 0; tj < 2; ++tj) {
      const float* b1p = b1 + (wid * 2 + tj) * 32 + khalf * 4;
      const float* w2p = W2 + (wid * 2 + tj) * 32 + khalf * 4;
#pragma unroll
      for (int rq = 0; rq < 4; ++rq) {
        const float4 b1q = *(const float4*)(b1p + rq * 8);
        const float4 w2q = *(const float4*)(w2p + rq * 8);
#pragma unroll
        for (int am = 0; am < 4; ++am) {
          sm[am] += fmaxf(acc[am][tj][rq * 4 + 0] + b1q.x, 0.f) * w2q.x;
          sm[am] += fmaxf(acc[am][tj][rq * 4 + 1] + b1q.y, 0.f) * w2q.y;
          sm[am] += fmaxf(acc[am][tj][rq * 4 + 2] + b1q.z, 0.f) * w2q.z;
          sm[am] += fmaxf(acc[am][tj][rq * 4 + 3] + b1q.w, 0.f) * w2q.w;
        }
      }
    }
#pragma unroll
    for (int am = 0; am < 4; ++am) sm[am] += __shfl_xor(sm[am], 32, 64);
    s0a = sm[0]; s1a = sm[1]; s2a = sm[2]; s3a = sm[3];
  }
  // psums in dedicated region beyond the A tile — no aliasing barrier needed
  float* psums = (float*)(As16 + 128 * 64);  // [128 pairs][9]
  {
    const float v0 = khalf ? s2a : s0a;
    const float v1 = khalf ? s3a : s1a;
    const int p0 = khalf * 64 + l31;       // am = khalf*2     -> pair base
    psums[p0 * 9 + wid] = v0;
    psums[(p0 + 32) * 9 + wid] = v1;       // am = khalf*2 + 1
  }
  __syncthreads();  // final barrier: psums visible
  if (tid < 128) {
    float t = b2[0];
#pragma unroll
    for (int w = 0; w < 8; ++w) t += psums[tid * 9 + w];
    out[(n0 + (tid >> 4)) * M_S + m0 + (tid & 15)] = 1.f / (1.f + __expf(-t));
  }
}

extern "C" void kernel_launch(void* const* d_in, const int* in_sizes, int n_in,
                              void* d_out, int out_size, void* d_ws, size_t ws_size,
                              hipStream_t stream) {
  const float* emb = (const float*)d_in[0];
  const float* sup = (const float*)d_in[1];
  const float* W1  = (const float*)d_in[2];
  const float* b1  = (const float*)d_in[3];
  const float* W2  = (const float*)d_in[4];
  const float* b2  = (const float*)d_in[5];
  float* out = (float*)d_out;
  unsigned short* w1s = (unsigned short*)d_ws;  // 512 KB fragment-ordered W1

  static bool attr_done = false;
  if (!attr_done) {
    hipFuncSetAttribute((const void*)support_kernel,
                        hipFuncAttributeMaxDynamicSharedMemorySize, 135680);
    attr_done = true;
  }

  prep_w1s<<<64, 1024, 0, stream>>>(W1, w1s);
  support_kernel<<<dim3(M_S / 16, N_Q / 8), 512, 135680, stream>>>(
      emb, sup, w1s, b1, W2, b2, out);
}

// Round 8
// 195.467 us; speedup vs baseline: 1.0029x; 1.0029x over previous
//
#include <hip/hip_runtime.h>
#include <hip/hip_bf16.h>

#define N_Q 256
#define M_S 1024
#define DD 512
#define HH 512

typedef __attribute__((ext_vector_type(8))) short short8;
typedef __attribute__((ext_vector_type(8))) __bf16 bf16x8;
typedef __attribute__((ext_vector_type(16))) float f32x16;
typedef __attribute__((ext_vector_type(2))) __bf16 bf16x2;

union U8 { short8 s; bf16x8 b; };

__device__ __forceinline__ unsigned short f2bf(float f) {
  unsigned int u = __float_as_uint(f);
  u += 0x7FFFu + ((u >> 16) & 1u);
  return (unsigned short)(u >> 16);
}

__device__ __forceinline__ short8 pack8(const float* d) {
#if defined(__has_builtin) && __has_builtin(__builtin_amdgcn_cvt_pk_bf16_f32)
  short8 r;
#pragma unroll
  for (int i = 0; i < 4; ++i) {
    union { bf16x2 v; short s[2]; } u;
    u.v = __builtin_amdgcn_cvt_pk_bf16_f32(d[2 * i], d[2 * i + 1]);
    r[2 * i] = u.s[0];
    r[2 * i + 1] = u.s[1];
  }
  return r;
#else
  short8 r;
#pragma unroll
  for (int i = 0; i < 8; ++i) r[i] = (short)f2bf(d[i]);
  return r;
#endif
}

__device__ __forceinline__ short8 packdiff(float4 e0, float4 e1, float4 s0, float4 s1) {
  float d[8];
  d[0] = fabsf(e0.x - s0.x); d[1] = fabsf(e0.y - s0.y);
  d[2] = fabsf(e0.z - s0.z); d[3] = fabsf(e0.w - s0.w);
  d[4] = fabsf(e1.x - s1.x); d[5] = fabsf(e1.y - s1.y);
  d[6] = fabsf(e1.z - s1.z); d[7] = fabsf(e1.w - s1.w);
  return pack8(d);
}

// W1 [D][H] fp32 -> w1s in MFMA-fragment order.
// Fragment map (verified): w1s[f*512 + l*8 + j] = W1[k][h] with
//   f = (k>>4)*16 + (h>>5), l = ((k>>3)&1)*32 + (h&31), j = k&7.
// Coalesced: 65536 threads, float4 read (4 h per thread), 4 stores.
__global__ __launch_bounds__(1024) void prep_w1s(const float* __restrict__ W1,
                                                 unsigned short* __restrict__ w1s) {
  const int gid = blockIdx.x * 1024 + threadIdx.x;  // 0..65535
  const int k = gid >> 7;                            // 0..511
  const int hq = gid & 127;                          // h-quad
  const float4 w = *(const float4*)(W1 + k * HH + hq * 4);
  const int f = (k >> 4) * 16 + (hq >> 3);
  const int lk = ((k >> 3) & 1) * 32 + (hq & 7) * 4; // l base for i=0
  const int j = k & 7;
  unsigned short* p = w1s + f * 512 + lk * 8 + j;    // stride 8 shorts per h
  p[0]  = f2bf(w.x);
  p[8]  = f2bf(w.y);
  p[16] = f2bf(w.z);
  p[24] = f2bf(w.w);
}

// Block: 512 thr = 8 waves. Tile 128 pairs (8 emb x 16 sup) x 512 h x K=512.
// A (diff) staged ONCE into 128 KB LDS, layout [p][c ^ (p&15)] (R7: 0 bank
// conflicts, keep). Wave wid = hslice (64 h); every wave covers all 128 pairs
// (acc[4][2]). MFMA operand-swapped; C col = pair, row = h.
// R8 change: NO GLOBAL LOADS IN THE K-LOOP. W1 fragments stream through a
// 32 KB double-buffered LDS FIFO via async global_load_lds, SELF-STAGED:
// wave wid stages only its own 2 KB/ks slice and reads only that slice ->
// zero cross-wave data flow, zero K-loop barriers. Per phase: 8 MFMA ->
// issue stage(ks+2) -> counted s_waitcnt vmcnt(2) (T4: never drain to 0) ->
// ds_read bw(ks+1) -> A-prefetch(ks+2). Only ~120cyc ds_read latency remains
// in-loop, prefetched 1-2 phases ahead. Theory: R1-R7's invariant ~1300
// cyc/ks was exposed L2/HBM latency on the in-loop W1 register loads
// (nothing was throughput-saturated: matrix 10%, LDS 29%, L2 20%).
// LDS: 131072 (A) + 32768 (FIFO) = 163840 B; psums alias As16 post-loop.
__global__ __launch_bounds__(512, 2) void support_kernel(
    const float* __restrict__ emb, const float* __restrict__ sup,
    const unsigned short* __restrict__ w1s, const float* __restrict__ b1,
    const float* __restrict__ W2, const float* __restrict__ b2,
    float* __restrict__ out) {
  extern __shared__ char lds[];
  short8* As16 = (short8*)lds;             // [128][64] chunks, 131072 B
  char* wbuf = lds + 131072;               // [2][8 waves][2048 B] = 32768 B

  const int tid = threadIdx.x;
  const int lane = tid & 63;
  const int wid = tid >> 6;          // 0..7 = hslice (h base = wid*64)
  const int l31 = lane & 31;
  const int khalf = lane >> 5;

  const int m0 = blockIdx.x * 16;
  const int n0 = blockIdx.y * 8;

  // per-lane global source base for this wave's W1 frag slice
  const char* gW = (const char*)w1s + (wid * 2) * 1024 + lane * 16;
  const int wslice = wid * 2048;     // wave-uniform LDS slice offset

#define STAGE_W1(KS) do {                                                     \
    const char* _g = gW + (KS) * 16384;                                       \
    char* _l = wbuf + (((KS) & 1) * 16384 + wslice);                          \
    __builtin_amdgcn_global_load_lds(                                         \
        (const __attribute__((address_space(1))) unsigned int*)(_g),          \
        (__attribute__((address_space(3))) unsigned int*)(_l), 16, 0, 0);     \
    __builtin_amdgcn_global_load_lds(                                         \
        (const __attribute__((address_space(1))) unsigned int*)(_g + 1024),   \
        (__attribute__((address_space(3))) unsigned int*)(_l + 1024), 16, 0, 0); \
  } while (0)

  // ---- stage 128p x 512k diffs (once): thread = (emb row rg, k-chunk c) ----
  {
    const int c = tid & 63;
    const int rg = tid >> 6;           // emb row 0..7
    const float* ep = emb + (n0 + rg) * DD + c * 8;
    const float4 e0 = *(const float4*)ep;
    const float4 e1 = *(const float4*)(ep + 4);
    const float* sbase = sup + m0 * DD + c * 8;
#pragma unroll
    for (int j = 0; j < 16; ++j) {     // 16 sup rows; p = rg*16+j, p&15 == j
      const float4 s0 = *(const float4*)(sbase + j * DD);
      const float4 s1 = *(const float4*)(sbase + j * DD + 4);
      As16[(rg * 16 + j) * 64 + (c ^ j)] = packdiff(e0, e1, s0, s1);
    }
  }
  // W1 FIFO prologue: stage ks=0,1 (drained by barrier's vmcnt(0))
  STAGE_W1(0);
  STAGE_W1(1);
  __syncthreads();  // barrier A: A-tile visible; all staging loads drained

  // ---- K-loop: 32 steps of 16 k, 8 MFMA each; barrier-free ----
  const int ax = l31 & 15;           // read-side chunk XOR (row&15 == l31&15)
  const int ar0 = (0 * 32 + l31) * 64;
  const int ar1 = (1 * 32 + l31) * 64;
  const int ar2 = (2 * 32 + l31) * 64;
  const int ar3 = (3 * 32 + l31) * 64;

  f32x16 acc[4][2] = {};
  U8 a[3][4];
#pragma unroll
  for (int s = 0; s < 2; ++s) {      // A prologue: ks=0,1
    const int c = (s * 2 + khalf) ^ ax;
    a[s][0].s = As16[ar0 + c];
    a[s][1].s = As16[ar1 + c];
    a[s][2].s = As16[ar2 + c];
    a[s][3].s = As16[ar3 + c];
  }
  U8 bw[2][2];
  {  // bw(0) from FIFO parity 0 (complete: barrier drained vmcnt)
    const short8* wp = (const short8*)(wbuf + wslice);
    bw[0][0].s = wp[lane];
    bw[0][1].s = wp[64 + lane];
  }

#pragma unroll
  for (int ks = 0; ks < 32; ++ks) {
    __builtin_amdgcn_s_setprio(1);
#pragma unroll
    for (int am = 0; am < 4; ++am)
#pragma unroll
      for (int tj = 0; tj < 2; ++tj)
        acc[am][tj] = __builtin_amdgcn_mfma_f32_32x32x16_bf16(
            bw[ks & 1][tj].b, a[ks % 3][am].b, acc[am][tj], 0, 0, 0);
    __builtin_amdgcn_s_setprio(0);
    if (ks + 2 < 32) {  // issue next-next W1 stage (async, vmcnt-counted)
      STAGE_W1(ks + 2);
      asm volatile("s_waitcnt vmcnt(2)" ::: "memory");  // stage(ks+1) landed
    } else if (ks == 30) {
      asm volatile("s_waitcnt vmcnt(0)" ::: "memory");  // stage(31) landed
    }
    if (ks + 1 < 32) {  // bw(ks+1) from FIFO
      const short8* wp =
          (const short8*)(wbuf + (((ks + 1) & 1) * 16384 + wslice));
      bw[(ks + 1) & 1][0].s = wp[lane];
      bw[(ks + 1) & 1][1].s = wp[64 + lane];
    }
    if (ks + 2 < 32) {  // A-frag prefetch, depth 2 (LDS)
      const int cc = ((ks + 2) * 2 + khalf) ^ ax;
      const int slot = (ks + 2) % 3;
      a[slot][0].s = As16[ar0 + cc];
      a[slot][1].s = As16[ar1 + cc];
      a[slot][2].s = As16[ar2 + cc];
      a[slot][3].s = As16[ar3 + cc];
    }
  }
#undef STAGE_W1

  // ---- epilogue: C col = pair (l31 + am*32), row = h: (r&3)+8*(r>>2)+4*khalf
  // In-lane reduce over 64 h per wave; one xor-32 shuffle per am.
  float s0a, s1a, s2a, s3a;
  {
    float sm[4] = {0.f, 0.f, 0.f, 0.f};
#pragma unroll
    for (int tj = 0; tj < 2; ++tj) {
      const float* b1p = b1 + (wid * 2 + tj) * 32 + khalf * 4;
      const float* w2p = W2 + (wid * 2 + tj) * 32 + khalf * 4;
#pragma unroll
      for (int rq = 0; rq < 4; ++rq) {
        const float4 b1q = *(const float4*)(b1p + rq * 8);
        const float4 w2q = *(const float4*)(w2p + rq * 8);
#pragma unroll
        for (int am = 0; am < 4; ++am) {
          sm[am] += fmaxf(acc[am][tj][rq * 4 + 0] + b1q.x, 0.f) * w2q.x;
          sm[am] += fmaxf(acc[am][tj][rq * 4 + 1] + b1q.y, 0.f) * w2q.y;
          sm[am] += fmaxf(acc[am][tj][rq * 4 + 2] + b1q.z, 0.f) * w2q.z;
          sm[am] += fmaxf(acc[am][tj][rq * 4 + 3] + b1q.w, 0.f) * w2q.w;
        }
      }
    }
#pragma unroll
    for (int am = 0; am < 4; ++am) sm[am] += __shfl_xor(sm[am], 32, 64);
    s0a = sm[0]; s1a = sm[1]; s2a = sm[2]; s3a = sm[3];
  }
  __syncthreads();  // all As16 reads done; safe to alias psums
  float* psums = (float*)As16;  // [128 pairs][9] (pad 9 -> conflict-free)
  {
    const float v0 = khalf ? s2a : s0a;
    const float v1 = khalf ? s3a : s1a;
    const int p0 = khalf * 64 + l31;       // am = khalf*2     -> pair base
    psums[p0 * 9 + wid] = v0;
    psums[(p0 + 32) * 9 + wid] = v1;       // am = khalf*2 + 1
  }
  __syncthreads();  // psums visible
  if (tid < 128) {
    float t = b2[0];
#pragma unroll
    for (int w = 0; w < 8; ++w) t += psums[tid * 9 + w];
    out[(n0 + (tid >> 4)) * M_S + m0 + (tid & 15)] = 1.f / (1.f + __expf(-t));
  }
}

extern "C" void kernel_launch(void* const* d_in, const int* in_sizes, int n_in,
                              void* d_out, int out_size, void* d_ws, size_t ws_size,
                              hipStream_t stream) {
  const float* emb = (const float*)d_in[0];
  const float* sup = (const float*)d_in[1];
  const float* W1  = (const float*)d_in[2];
  const float* b1  = (const float*)d_in[3];
  const float* W2  = (const float*)d_in[4];
  const float* b2  = (const float*)d_in[5];
  float* out = (float*)d_out;
  unsigned short* w1s = (unsigned short*)d_ws;  // 512 KB fragment-ordered W1

  static bool attr_done = false;
  if (!attr_done) {
    hipFuncSetAttribute((const void*)support_kernel,
                        hipFuncAttributeMaxDynamicSharedMemorySize, 163840);
    attr_done = true;
  }

  prep_w1s<<<64, 1024, 0, stream>>>(W1, w1s);
  support_kernel<<<dim3(M_S / 16, N_Q / 8), 512, 163840, stream>>>(
      emb, sup, w1s, b1, W2, b2, out);
}